// Round 1
// baseline (978.472 us; speedup 1.0000x reference)
//
#include <hip/hip_runtime.h>

typedef short short8 __attribute__((ext_vector_type(8)));
typedef unsigned short ushort8v __attribute__((ext_vector_type(8)));
typedef unsigned short ushort4v __attribute__((ext_vector_type(4)));
typedef float f32x4 __attribute__((ext_vector_type(4)));

#define USH unsigned short

__device__ __forceinline__ USH f2bf(float f) {
  unsigned int u = __builtin_bit_cast(unsigned int, f);
  u = (u + 0x7FFFu + ((u >> 16) & 1u)) >> 16;
  return (USH)u;
}

__device__ __forceinline__ f32x4 mfma16(short8 a, short8 b, f32x4 c) {
  return __builtin_amdgcn_mfma_f32_16x16x32_bf16(a, b, c, 0, 0, 0);
}

// ---------------- fp32 -> bf16 convert ----------------
__global__ __launch_bounds__(256) void cvt_bf16(const float* __restrict__ in,
                                                USH* __restrict__ out, int n4) {
  int i = blockIdx.x * 256 + threadIdx.x;
  if (i >= n4) return;
  f32x4 v = *(const f32x4*)(in + (size_t)i * 4);
  ushort4v o;
#pragma unroll
  for (int k = 0; k < 4; k++) o[k] = f2bf(v[k]);
  *(ushort4v*)(out + (size_t)i * 4) = o;
}

// ---------------- GEMM: C[M,N] = A[M,K] @ B[N,K]^T + bias ----------------
// A, B bf16 (row-major, K contiguous). OUT_F32: write fp32 else bf16.
template <bool OUT_F32>
__global__ __launch_bounds__(256) void gemm_bt(const USH* __restrict__ A,
                                               const USH* __restrict__ B,
                                               const float* __restrict__ bias,
                                               void* __restrict__ Cout,
                                               int M, int N, int K) {
  __shared__ __align__(16) USH As[128][72];
  __shared__ __align__(16) USH Bs[128][72];
  const int tid = threadIdx.x;
  const int row0 = blockIdx.x * 128;
  const int col0 = blockIdx.y * 128;
  const int wid = tid >> 6, lane = tid & 63;
  const int wr = (wid >> 1) * 64, wc = (wid & 1) * 64;
  const int lmod = lane & 15, ldiv = lane >> 4;

  f32x4 acc[4][4];
#pragma unroll
  for (int i = 0; i < 4; i++)
#pragma unroll
    for (int j = 0; j < 4; j++) acc[i][j] = (f32x4){0.f, 0.f, 0.f, 0.f};

  const USH* Ab = A + (size_t)row0 * K;
  const USH* Bb = B + (size_t)col0 * K;
  const int sr = tid >> 3;        // 0..31
  const int sc = (tid & 7) * 8;   // 0..56

  for (int k0 = 0; k0 < K; k0 += 64) {
    __syncthreads();
#pragma unroll
    for (int c = 0; c < 4; c++) {
      int r = sr + c * 32;
      *(short8*)&As[r][sc] = *(const short8*)&Ab[(size_t)r * K + k0 + sc];
      *(short8*)&Bs[r][sc] = *(const short8*)&Bb[(size_t)r * K + k0 + sc];
    }
    __syncthreads();
#pragma unroll
    for (int kk = 0; kk < 64; kk += 32) {
      short8 a[4], b[4];
#pragma unroll
      for (int i = 0; i < 4; i++)
        a[i] = *(const short8*)&As[wr + i * 16 + lmod][kk + ldiv * 8];
#pragma unroll
      for (int i = 0; i < 4; i++)
        b[i] = *(const short8*)&Bs[wc + i * 16 + lmod][kk + ldiv * 8];
#pragma unroll
      for (int i = 0; i < 4; i++)
#pragma unroll
        for (int j = 0; j < 4; j++)
          acc[i][j] = mfma16(a[i], b[j], acc[i][j]);
    }
  }

  const int r4 = ldiv * 4;
#pragma unroll
  for (int i = 0; i < 4; i++) {
#pragma unroll
    for (int j = 0; j < 4; j++) {
      int rr = row0 + wr + i * 16 + r4;
      int cc = col0 + wc + j * 16 + lmod;
      float bv = bias[cc];
#pragma unroll
      for (int t = 0; t < 4; t++) {
        float v = acc[i][j][t] + bv;
        if (OUT_F32)
          ((float*)Cout)[(size_t)(rr + t) * N + cc] = v;
        else
          ((USH*)Cout)[(size_t)(rr + t) * N + cc] = f2bf(v);
      }
    }
  }
}

// ---------------- V transpose: vT[bh][dh][s] = qkv[b][s][1024 + h*64 + dh] ----------------
__global__ __launch_bounds__(256) void vtrans(const USH* __restrict__ qkv,
                                              USH* __restrict__ vT) {
  __shared__ __align__(16) USH t[64][72];
  const int bh = blockIdx.y, b = bh >> 3, h = bh & 7;
  const int s0 = blockIdx.x * 64;
  const int tid = threadIdx.x;
  const int r = tid >> 4, c4 = (tid & 15) * 4;
#pragma unroll
  for (int i = 0; i < 4; i++) {
    int row = r + i * 16;
    *(ushort4v*)&t[row][c4] =
        *(const ushort4v*)&qkv[(size_t)(b * 4096 + s0 + row) * 1536 + 1024 + h * 64 + c4];
  }
  __syncthreads();
  const int d = tid >> 2, sb = (tid & 3) * 16;
  size_t ob = (size_t)(bh * 64 + d) * 4096 + s0 + sb;
#pragma unroll
  for (int half = 0; half < 2; half++) {
    ushort8v o;
#pragma unroll
    for (int k = 0; k < 8; k++) o[k] = t[sb + half * 8 + k][d];
    *(ushort8v*)&vT[ob + half * 8] = o;
  }
}

// ---------------- Flash attention ----------------
// grid: (S/64, B*H). block: 256 (4 waves, 16 q-rows each). KB=128 keys/iter.
__global__ __launch_bounds__(256) void attn_fwd(const USH* __restrict__ qkv,
                                                const USH* __restrict__ vT,
                                                USH* __restrict__ attno) {
  __shared__ __align__(16) USH p_lds[4][16][136];
  const int bh = blockIdx.y;
  const int b = bh >> 3, h = bh & 7;
  const int wid = threadIdx.x >> 6, lane = threadIdx.x & 63;
  const int lmod = lane & 15, ldiv = lane >> 4;
  const int qrow = blockIdx.x * 64 + wid * 16;

  const USH* qp = qkv + (size_t)(b * 4096 + qrow + lmod) * 1536 + h * 64 + ldiv * 8;
  short8 qf0 = *(const short8*)qp;
  short8 qf1 = *(const short8*)(qp + 32);

  f32x4 acco[4];
  f32x4 l_acc = (f32x4){0.f, 0.f, 0.f, 0.f};
  float m_r[4];
#pragma unroll
  for (int n = 0; n < 4; n++) acco[n] = (f32x4){0.f, 0.f, 0.f, 0.f};
#pragma unroll
  for (int j = 0; j < 4; j++) m_r[j] = -1e30f;

  short8 ones;
#pragma unroll
  for (int i = 0; i < 8; i++) ones[i] = (short)0x3F80;  // bf16 1.0

  const USH* kb = qkv + (size_t)b * 4096 * 1536 + 512 + h * 64 + ldiv * 8;
  const USH* vb = vT + ((size_t)bh * 64 + lmod) * 4096 + ldiv * 8;
  const float K2 = 0.18033688011112042f;  // log2(e)/8  (scale 1/sqrt(64) folded in)

  for (int k0 = 0; k0 < 4096; k0 += 128) {
    f32x4 s[8];
#pragma unroll
    for (int n = 0; n < 8; n++) s[n] = (f32x4){0.f, 0.f, 0.f, 0.f};
#pragma unroll
    for (int n = 0; n < 8; n++) {
      const USH* kp = kb + (size_t)(k0 + n * 16 + lmod) * 1536;
      short8 kf0 = *(const short8*)kp;
      short8 kf1 = *(const short8*)(kp + 32);
      s[n] = mfma16(qf0, kf0, s[n]);
      s[n] = mfma16(qf1, kf1, s[n]);
    }
    float alpha[4], mK2[4];
#pragma unroll
    for (int j = 0; j < 4; j++) {
      float v = s[0][j];
#pragma unroll
      for (int n = 1; n < 8; n++) v = fmaxf(v, s[n][j]);
      v = fmaxf(v, __shfl_xor(v, 1));
      v = fmaxf(v, __shfl_xor(v, 2));
      v = fmaxf(v, __shfl_xor(v, 4));
      v = fmaxf(v, __shfl_xor(v, 8));
      float mn = fmaxf(m_r[j], v);
      alpha[j] = exp2f((m_r[j] - mn) * K2);
      m_r[j] = mn;
      mK2[j] = mn * K2;
    }
#pragma unroll
    for (int n = 0; n < 8; n++) {
#pragma unroll
      for (int j = 0; j < 4; j++) {
        float p = exp2f(fmaf(s[n][j], K2, -mK2[j]));
        p_lds[wid][ldiv * 4 + j][n * 16 + lmod] = f2bf(p);
      }
    }
#pragma unroll
    for (int n = 0; n < 4; n++) {
#pragma unroll
      for (int j = 0; j < 4; j++) acco[n][j] *= alpha[j];
    }
#pragma unroll
    for (int j = 0; j < 4; j++) l_acc[j] *= alpha[j];
#pragma unroll
    for (int kc = 0; kc < 4; kc++) {
      short8 pf = *(const short8*)&p_lds[wid][lmod][kc * 32 + ldiv * 8];
      l_acc = mfma16(pf, ones, l_acc);  // row-sum of P via MFMA (no shuffle reduce)
#pragma unroll
      for (int n = 0; n < 4; n++) {
        short8 vf = *(const short8*)(vb + (size_t)n * 16 * 4096 + k0 + kc * 32);
        acco[n] = mfma16(pf, vf, acco[n]);
      }
    }
  }
  float invl[4];
#pragma unroll
  for (int j = 0; j < 4; j++) invl[j] = 1.0f / l_acc[j];
  USH* ob = attno + (size_t)(b * 4096 + qrow) * 512 + h * 64;
#pragma unroll
  for (int n = 0; n < 4; n++) {
#pragma unroll
    for (int j = 0; j < 4; j++) {
      ob[(size_t)(ldiv * 4 + j) * 512 + n * 16 + lmod] = f2bf(acco[n][j] * invl[j]);
    }
  }
}

// ---------------- launch ----------------
extern "C" void kernel_launch(void* const* d_in, const int* in_sizes, int n_in,
                              void* d_out, int out_size, void* d_ws, size_t ws_size,
                              hipStream_t stream) {
  const float* x = (const float*)d_in[0];      // (4,4096,512)
  const float* w_in = (const float*)d_in[1];   // (1536,512)
  const float* b_in = (const float*)d_in[2];   // (1536)
  const float* w_out = (const float*)d_in[3];  // (512,512)
  const float* b_out = (const float*)d_in[4];  // (512)
  float* out = (float*)d_out;                  // (4,4096,512) fp32

  char* ws = (char*)d_ws;
  USH* xb = (USH*)(ws);                        // 16 MB  (reused as attno later)
  USH* winb = (USH*)(ws + 16777216);           // 1.5 MB
  USH* woutb = (USH*)(ws + 18350080);          // 0.5 MB
  USH* qkv = (USH*)(ws + 18874368);            // 48 MB
  USH* vT = (USH*)(ws + 69206016);             // 16 MB
  USH* attno = xb;                             // alias: xb dead after gemm1

  cvt_bf16<<<8192, 256, 0, stream>>>(x, xb, 2097152);
  cvt_bf16<<<768, 256, 0, stream>>>(w_in, winb, 196608);
  cvt_bf16<<<256, 256, 0, stream>>>(w_out, woutb, 65536);

  gemm_bt<false><<<dim3(128, 12), 256, 0, stream>>>(xb, winb, b_in, qkv, 16384, 1536, 512);
  vtrans<<<dim3(64, 32), 256, 0, stream>>>(qkv, vT);
  attn_fwd<<<dim3(64, 32), 256, 0, stream>>>(qkv, vT, attno);
  gemm_bt<true><<<dim3(128, 4), 256, 0, stream>>>(attno, woutb, b_out, out, 16384, 512, 512);
}

// Round 2
// 425.596 us; speedup vs baseline: 2.2991x; 2.2991x over previous
//
#include <hip/hip_runtime.h>

typedef short short8 __attribute__((ext_vector_type(8)));
typedef unsigned short ushort8v __attribute__((ext_vector_type(8)));
typedef unsigned short ushort4v __attribute__((ext_vector_type(4)));
typedef float f32x4 __attribute__((ext_vector_type(4)));

#define USH unsigned short

__device__ __forceinline__ USH f2bf(float f) {
  unsigned int u = __builtin_bit_cast(unsigned int, f);
  u = (u + 0x7FFFu + ((u >> 16) & 1u)) >> 16;
  return (USH)u;
}

__device__ __forceinline__ f32x4 mfma16(short8 a, short8 b, f32x4 c) {
  return __builtin_amdgcn_mfma_f32_16x16x32_bf16(a, b, c, 0, 0, 0);
}

// async global->LDS, 16B per lane, dest = base + lane*16 (linear)
__device__ __forceinline__ void gload16(const USH* g, USH* l) {
  __builtin_amdgcn_global_load_lds(
      (const __attribute__((address_space(1))) unsigned int*)g,
      (__attribute__((address_space(3))) unsigned int*)l, 16, 0, 0);
}

// cross-lane max over the 16-lane DPP row (covers lmod group)
template <int CTRL>
__device__ __forceinline__ float dppmaxstep(float x) {
  int xi = __builtin_bit_cast(int, x);
  int yi = __builtin_amdgcn_update_dpp(xi, xi, CTRL, 0xF, 0xF, true);
  return fmaxf(x, __builtin_bit_cast(float, yi));
}
__device__ __forceinline__ float rowmax16(float x) {
  x = dppmaxstep<0xB1>(x);   // quad_perm xor1
  x = dppmaxstep<0x4E>(x);   // quad_perm xor2
  x = dppmaxstep<0x141>(x);  // row_half_mirror
  x = dppmaxstep<0x140>(x);  // row_mirror
  return x;
}

// ---------------- fp32 -> bf16 convert ----------------
__global__ __launch_bounds__(256) void cvt_bf16(const float* __restrict__ in,
                                                USH* __restrict__ out, int n4) {
  int i = blockIdx.x * 256 + threadIdx.x;
  if (i >= n4) return;
  f32x4 v = *(const f32x4*)(in + (size_t)i * 4);
  ushort4v o;
#pragma unroll
  for (int k = 0; k < 4; k++) o[k] = f2bf(v[k]);
  *(ushort4v*)(out + (size_t)i * 4) = o;
}

// ---------------- GEMM: C[M,N] = A[M,K] @ B[N,K]^T + bias ----------------
// m97 structure: 128x128 tile, BK=64, global_load_lds staging, swizzled reads.
template <bool OUT_F32>
__global__ __launch_bounds__(256) void gemm_bt(const USH* __restrict__ A,
                                               const USH* __restrict__ B,
                                               const float* __restrict__ bias,
                                               void* __restrict__ Cout,
                                               int M, int N, int K) {
  __shared__ __align__(16) USH As[128 * 64];
  __shared__ __align__(16) USH Bs[128 * 64];
  const int tid = threadIdx.x;
  const int row0 = blockIdx.x * 128;
  const int col0 = blockIdx.y * 128;
  const int wid = tid >> 6, lane = tid & 63;
  const int wr = (wid >> 1) * 64, wc = (wid & 1) * 64;
  const int lmod = lane & 15, ldiv = lane >> 4;
  const int asw = lmod & 7;
  const int srow = lane >> 3;                  // 0..7
  const int scol = ((lane & 7) ^ srow) * 8;    // pre-swizzled global col

  f32x4 acc[4][4];
#pragma unroll
  for (int i = 0; i < 4; i++)
#pragma unroll
    for (int j = 0; j < 4; j++) acc[i][j] = (f32x4){0.f, 0.f, 0.f, 0.f};

  const USH* Ab = A + (size_t)row0 * K;
  const USH* Bb = B + (size_t)col0 * K;

  for (int k0 = 0; k0 < K; k0 += 64) {
    __syncthreads();
#pragma unroll
    for (int i = 0; i < 4; i++) {
      int r0 = wid * 32 + i * 8;
      int r = r0 + srow;
      gload16(&Ab[(size_t)r * K + k0 + scol], &As[r0 * 64]);
      gload16(&Bb[(size_t)r * K + k0 + scol], &Bs[r0 * 64]);
    }
    __syncthreads();
#pragma unroll
    for (int kk = 0; kk < 64; kk += 32) {
      short8 a[4], b[4];
#pragma unroll
      for (int i = 0; i < 4; i++)
        a[i] = *(const short8*)&As[(wr + i * 16 + lmod) * 64 +
                                   ((((kk >> 3) + ldiv) ^ asw) << 3)];
#pragma unroll
      for (int i = 0; i < 4; i++)
        b[i] = *(const short8*)&Bs[(wc + i * 16 + lmod) * 64 +
                                   ((((kk >> 3) + ldiv) ^ asw) << 3)];
#pragma unroll
      for (int i = 0; i < 4; i++)
#pragma unroll
        for (int j = 0; j < 4; j++)
          acc[i][j] = mfma16(a[i], b[j], acc[i][j]);
    }
  }

  const int r4 = ldiv * 4;
#pragma unroll
  for (int i = 0; i < 4; i++) {
#pragma unroll
    for (int j = 0; j < 4; j++) {
      int rr = row0 + wr + i * 16 + r4;
      int cc = col0 + wc + j * 16 + lmod;
      float bv = bias[cc];
#pragma unroll
      for (int t = 0; t < 4; t++) {
        float v = acc[i][j][t] + bv;
        if (OUT_F32)
          ((float*)Cout)[(size_t)(rr + t) * N + cc] = v;
        else
          ((USH*)Cout)[(size_t)(rr + t) * N + cc] = f2bf(v);
      }
    }
  }
}

// ---------------- V transpose: vT[bh][dh][s] = qkv[b][s][1024 + h*64 + dh] ----------------
__global__ __launch_bounds__(256) void vtrans(const USH* __restrict__ qkv,
                                              USH* __restrict__ vT) {
  __shared__ __align__(16) USH t[64][72];
  const int bh = blockIdx.y, b = bh >> 3, h = bh & 7;
  const int s0 = blockIdx.x * 64;
  const int tid = threadIdx.x;
  const int r = tid >> 4, c4 = (tid & 15) * 4;
#pragma unroll
  for (int i = 0; i < 4; i++) {
    int row = r + i * 16;
    *(ushort4v*)&t[row][c4] =
        *(const ushort4v*)&qkv[(size_t)(b * 4096 + s0 + row) * 1536 + 1024 + h * 64 + c4];
  }
  __syncthreads();
  const int d = tid >> 2, sb = (tid & 3) * 16;
  size_t ob = (size_t)(bh * 64 + d) * 4096 + s0 + sb;
#pragma unroll
  for (int half = 0; half < 2; half++) {
    ushort8v o;
#pragma unroll
    for (int k = 0; k < 8; k++) o[k] = t[sb + half * 8 + k][d];
    *(ushort8v*)&vT[ob + half * 8] = o;
  }
}

// ---------------- Flash attention v2 ----------------
// 1024 blocks (XCD-swizzled), 256 thr = 4 waves, wave = 32 q-rows, KVBLK=64,
// K/V double-buffered LDS via global_load_lds with XOR-swizzle (both sides).
__global__ __launch_bounds__(256, 3) void attn_fwd(const USH* __restrict__ qkv,
                                                   const USH* __restrict__ vT,
                                                   USH* __restrict__ attno) {
  __shared__ __align__(16) USH Ks[2][64 * 64];   // 16 KB
  __shared__ __align__(16) USH Vs[2][64 * 64];   // 16 KB
  __shared__ __align__(16) USH Ps[4][32 * 64];   // 16 KB (per-wave P)

  // XCD swizzle: all 32 q-blocks of a bh share an XCD (flat%8 constant)
  const int fb = blockIdx.x;
  const int b3 = fb & 7;
  const int rest = fb >> 3;
  const int qb = rest & 31;
  const int bh = b3 + 8 * (rest >> 5);
  const int b = bh >> 3, h = bh & 7;

  const int wid = threadIdx.x >> 6, lane = threadIdx.x & 63;
  const int lmod = lane & 15, ldiv = lane >> 4;
  const int ksw = lmod & 7;
  const int qrow0 = qb * 128 + wid * 32;

  // Q fragments (2 row-groups x 2 dh-halves)
  short8 qf00, qf01, qf10, qf11;
  {
    const USH* qp = qkv + (size_t)(b * 4096 + qrow0 + lmod) * 1536 + h * 64 + ldiv * 8;
    qf00 = *(const short8*)qp;
    qf01 = *(const short8*)(qp + 32);
    qp += (size_t)16 * 1536;
    qf10 = *(const short8*)qp;
    qf11 = *(const short8*)(qp + 32);
  }

  short8 ones;
#pragma unroll
  for (int i = 0; i < 8; i++) ones[i] = (short)0x3F80;  // bf16 1.0

  f32x4 acc0[4], acc1[4];
#pragma unroll
  for (int n = 0; n < 4; n++) {
    acc0[n] = (f32x4){0.f, 0.f, 0.f, 0.f};
    acc1[n] = (f32x4){0.f, 0.f, 0.f, 0.f};
  }
  f32x4 l0 = (f32x4){0.f, 0.f, 0.f, 0.f}, l1 = l0;
  f32x4 m0 = (f32x4){-1e30f, -1e30f, -1e30f, -1e30f}, m1 = m0;

  const USH* kbase = qkv + (size_t)b * 4096 * 1536 + 512 + h * 64;
  const USH* vbase = vT + (size_t)bh * 64 * 4096;
  const int srow = lane >> 3;               // 0..7
  const int scol = ((lane & 7) ^ srow) * 8; // pre-swizzled global col offset
  const float K2 = 0.18033688011112042f;    // log2(e)/8

  auto stage = [&](int bu, int k0) {
#pragma unroll
    for (int i = 0; i < 2; ++i) {
      int r0 = wid * 16 + i * 8;
      int r = r0 + srow;
      gload16(kbase + (size_t)(k0 + r) * 1536 + scol, &Ks[bu][r0 * 64]);
      gload16(vbase + (size_t)r * 4096 + k0 + scol, &Vs[bu][r0 * 64]);
    }
  };

  stage(0, 0);  // prologue

  for (int t = 0; t < 64; ++t) {
    const int cur = t & 1;
    __syncthreads();  // drains vmcnt(0): buf[cur] ready; prev reads of buf[cur^1] done
    if (t < 63) stage(cur ^ 1, (t + 1) * 64);

    const USH* Kc = &Ks[cur][0];
    const USH* Vc = &Vs[cur][0];
    USH* Pw = &Ps[wid][0];

    // ---- QK^T ----
    f32x4 s0[4], s1[4];
#pragma unroll
    for (int n = 0; n < 4; n++) {
      s0[n] = (f32x4){0.f, 0.f, 0.f, 0.f};
      s1[n] = (f32x4){0.f, 0.f, 0.f, 0.f};
    }
#pragma unroll
    for (int n = 0; n < 4; n++) {
      const USH* kr = Kc + (n * 16 + lmod) * 64;
      short8 kf0 = *(const short8*)(kr + ((ldiv ^ ksw) << 3));
      short8 kf1 = *(const short8*)(kr + (((4 + ldiv) ^ ksw) << 3));
      s0[n] = mfma16(qf00, kf0, s0[n]);
      s0[n] = mfma16(qf01, kf1, s0[n]);
      s1[n] = mfma16(qf10, kf0, s1[n]);
      s1[n] = mfma16(qf11, kf1, s1[n]);
    }

    // ---- online softmax (DPP row-max, no DS traffic) ----
    f32x4 al0, al1;
#pragma unroll
    for (int j = 0; j < 4; j++) {
      float v = fmaxf(fmaxf(s0[0][j], s0[1][j]), fmaxf(s0[2][j], s0[3][j]));
      v = rowmax16(v);
      float mn = fmaxf(m0[j], v);
      al0[j] = exp2f((m0[j] - mn) * K2);
      m0[j] = mn;
    }
#pragma unroll
    for (int j = 0; j < 4; j++) {
      float v = fmaxf(fmaxf(s1[0][j], s1[1][j]), fmaxf(s1[2][j], s1[3][j]));
      v = rowmax16(v);
      float mn = fmaxf(m1[j], v);
      al1[j] = exp2f((m1[j] - mn) * K2);
      m1[j] = mn;
    }

    // ---- P = exp2((s-m)*K2) -> swizzled per-wave LDS ----
#pragma unroll
    for (int n = 0; n < 4; n++) {
#pragma unroll
      for (int j = 0; j < 4; j++) {
        int r = ldiv * 4 + j;
        int col = n * 16 + lmod;
        Pw[(r * 64 + col) ^ ((r & 7) << 3)] = f2bf(exp2f((s0[n][j] - m0[j]) * K2));
        Pw[((16 + r) * 64 + col) ^ ((r & 7) << 3)] = f2bf(exp2f((s1[n][j] - m1[j]) * K2));
      }
    }

    // ---- rescale ----
#pragma unroll
    for (int n = 0; n < 4; n++) {
      acc0[n] *= al0;
      acc1[n] *= al1;
    }
    l0 *= al0;
    l1 *= al1;

    // ---- PV (+ row-sum via ones-MFMA) ----
#pragma unroll
    for (int kc = 0; kc < 2; kc++) {
      const int off = kc * 32 + ldiv * 8;
      short8 pf0 = *(const short8*)&Pw[(lmod * 64 + off) ^ (ksw << 3)];
      short8 pf1 = *(const short8*)&Pw[((16 + lmod) * 64 + off) ^ (ksw << 3)];
      l0 = mfma16(pf0, ones, l0);
      l1 = mfma16(pf1, ones, l1);
#pragma unroll
      for (int n = 0; n < 4; n++) {
        const USH* vr = Vc + (n * 16 + lmod) * 64;
        short8 vf = *(const short8*)(vr + (((kc * 4 + ldiv) ^ ksw) << 3));
        acc0[n] = mfma16(pf0, vf, acc0[n]);
        acc1[n] = mfma16(pf1, vf, acc1[n]);
      }
    }
  }

  // ---- epilogue ----
  float iv0[4], iv1[4];
#pragma unroll
  for (int j = 0; j < 4; j++) {
    iv0[j] = 1.0f / l0[j];
    iv1[j] = 1.0f / l1[j];
  }
  USH* ob = attno + (size_t)(b * 4096 + qrow0) * 512 + h * 64;
#pragma unroll
  for (int n = 0; n < 4; n++) {
#pragma unroll
    for (int j = 0; j < 4; j++) {
      ob[(size_t)(ldiv * 4 + j) * 512 + n * 16 + lmod] = f2bf(acc0[n][j] * iv0[j]);
      ob[(size_t)(16 + ldiv * 4 + j) * 512 + n * 16 + lmod] = f2bf(acc1[n][j] * iv1[j]);
    }
  }
}

// ---------------- launch ----------------
extern "C" void kernel_launch(void* const* d_in, const int* in_sizes, int n_in,
                              void* d_out, int out_size, void* d_ws, size_t ws_size,
                              hipStream_t stream) {
  const float* x = (const float*)d_in[0];      // (4,4096,512)
  const float* w_in = (const float*)d_in[1];   // (1536,512)
  const float* b_in = (const float*)d_in[2];   // (1536)
  const float* w_out = (const float*)d_in[3];  // (512,512)
  const float* b_out = (const float*)d_in[4];  // (512)
  float* out = (float*)d_out;                  // (4,4096,512) fp32

  char* ws = (char*)d_ws;
  USH* xb = (USH*)(ws);                        // 16 MB  (reused as attno later)
  USH* winb = (USH*)(ws + 16777216);           // 1.5 MB
  USH* woutb = (USH*)(ws + 18350080);          // 0.5 MB
  USH* qkv = (USH*)(ws + 18874368);            // 48 MB
  USH* vT = (USH*)(ws + 69206016);             // 16 MB
  USH* attno = xb;                             // alias: xb dead after gemm1

  cvt_bf16<<<8192, 256, 0, stream>>>(x, xb, 2097152);
  cvt_bf16<<<768, 256, 0, stream>>>(w_in, winb, 196608);
  cvt_bf16<<<256, 256, 0, stream>>>(w_out, woutb, 65536);

  gemm_bt<false><<<dim3(128, 12), 256, 0, stream>>>(xb, winb, b_in, qkv, 16384, 1536, 512);
  vtrans<<<dim3(64, 32), 256, 0, stream>>>(qkv, vT);
  attn_fwd<<<1024, 256, 0, stream>>>(qkv, vT, attno);
  gemm_bt<true><<<dim3(128, 4), 256, 0, stream>>>(attno, woutb, b_out, out, 16384, 512, 512);
}

// Round 6
// 349.558 us; speedup vs baseline: 2.7992x; 1.2175x over previous
//
#include <hip/hip_runtime.h>

typedef short short8 __attribute__((ext_vector_type(8)));
typedef unsigned short ushort8v __attribute__((ext_vector_type(8)));
typedef unsigned short ushort4v __attribute__((ext_vector_type(4)));
typedef float f32x4 __attribute__((ext_vector_type(4)));

#define USH unsigned short

__device__ __forceinline__ USH f2bf(float f) {
  unsigned int u = __builtin_bit_cast(unsigned int, f);
  u = (u + 0x7FFFu + ((u >> 16) & 1u)) >> 16;
  return (USH)u;
}

__device__ __forceinline__ f32x4 mfma16(short8 a, short8 b, f32x4 c) {
  return __builtin_amdgcn_mfma_f32_16x16x32_bf16(a, b, c, 0, 0, 0);
}

// async global->LDS, 16B per lane, dest = base + lane*16 (linear)
__device__ __forceinline__ void gload16(const USH* g, USH* l) {
  __builtin_amdgcn_global_load_lds(
      (const __attribute__((address_space(1))) unsigned int*)g,
      (__attribute__((address_space(3))) unsigned int*)l, 16, 0, 0);
}

// cross-lane max over the 16-lane DPP row (covers lmod group) — r2-verified
template <int CTRL>
__device__ __forceinline__ float dppmaxstep(float x) {
  int xi = __builtin_bit_cast(int, x);
  int yi = __builtin_amdgcn_update_dpp(xi, xi, CTRL, 0xF, 0xF, true);
  return fmaxf(x, __builtin_bit_cast(float, yi));
}
__device__ __forceinline__ float rowmax16(float x) {
  x = dppmaxstep<0xB1>(x);   // quad_perm xor1
  x = dppmaxstep<0x4E>(x);   // quad_perm xor2
  x = dppmaxstep<0x141>(x);  // row_half_mirror
  x = dppmaxstep<0x140>(x);  // row_mirror
  return x;
}

__device__ __forceinline__ f32x4 vmax4(f32x4 a, f32x4 b) {
  f32x4 r;
  r[0] = fmaxf(a[0], b[0]);
  r[1] = fmaxf(a[1], b[1]);
  r[2] = fmaxf(a[2], b[2]);
  r[3] = fmaxf(a[3], b[3]);
  return r;
}

// ---------------- fp32 -> bf16 convert ----------------
__global__ __launch_bounds__(256) void cvt_bf16(const float* __restrict__ in,
                                                USH* __restrict__ out, int n4) {
  int i = blockIdx.x * 256 + threadIdx.x;
  if (i >= n4) return;
  f32x4 v = *(const f32x4*)(in + (size_t)i * 4);
  ushort4v o;
#pragma unroll
  for (int k = 0; k < 4; k++) o[k] = f2bf(v[k]);
  *(ushort4v*)(out + (size_t)i * 4) = o;
}

// ---------------- GEMM: C[M,N] = A[M,K] @ B[N,K]^T + bias ----------------
// m97 structure: 128x128 tile, BK=64, global_load_lds staging, swizzled reads.
template <bool OUT_F32>
__global__ __launch_bounds__(256) void gemm_bt(const USH* __restrict__ A,
                                               const USH* __restrict__ B,
                                               const float* __restrict__ bias,
                                               void* __restrict__ Cout,
                                               int M, int N, int K) {
  __shared__ __align__(16) USH As[128 * 64];
  __shared__ __align__(16) USH Bs[128 * 64];
  const int tid = threadIdx.x;
  const int row0 = blockIdx.x * 128;
  const int col0 = blockIdx.y * 128;
  const int wid = tid >> 6, lane = tid & 63;
  const int wr = (wid >> 1) * 64, wc = (wid & 1) * 64;
  const int lmod = lane & 15, ldiv = lane >> 4;
  const int asw = lmod & 7;
  const int srow = lane >> 3;
  const int scol = ((lane & 7) ^ srow) * 8;

  f32x4 acc[4][4];
#pragma unroll
  for (int i = 0; i < 4; i++)
#pragma unroll
    for (int j = 0; j < 4; j++) acc[i][j] = (f32x4){0.f, 0.f, 0.f, 0.f};

  const USH* Ab = A + (size_t)row0 * K;
  const USH* Bb = B + (size_t)col0 * K;

  for (int k0 = 0; k0 < K; k0 += 64) {
    __syncthreads();
#pragma unroll
    for (int i = 0; i < 4; i++) {
      int r0 = wid * 32 + i * 8;
      int r = r0 + srow;
      gload16(&Ab[(size_t)r * K + k0 + scol], &As[r0 * 64]);
      gload16(&Bb[(size_t)r * K + k0 + scol], &Bs[r0 * 64]);
    }
    __syncthreads();
#pragma unroll
    for (int kk = 0; kk < 64; kk += 32) {
      short8 a[4], b[4];
#pragma unroll
      for (int i = 0; i < 4; i++)
        a[i] = *(const short8*)&As[(wr + i * 16 + lmod) * 64 +
                                   ((((kk >> 3) + ldiv) ^ asw) << 3)];
#pragma unroll
      for (int i = 0; i < 4; i++)
        b[i] = *(const short8*)&Bs[(wc + i * 16 + lmod) * 64 +
                                   ((((kk >> 3) + ldiv) ^ asw) << 3)];
#pragma unroll
      for (int i = 0; i < 4; i++)
#pragma unroll
        for (int j = 0; j < 4; j++)
          acc[i][j] = mfma16(a[i], b[j], acc[i][j]);
    }
  }

  const int r4 = ldiv * 4;
#pragma unroll
  for (int i = 0; i < 4; i++) {
#pragma unroll
    for (int j = 0; j < 4; j++) {
      int rr = row0 + wr + i * 16 + r4;
      int cc = col0 + wc + j * 16 + lmod;
      float bv = bias[cc];
#pragma unroll
      for (int t = 0; t < 4; t++) {
        float v = acc[i][j][t] + bv;
        if (OUT_F32)
          ((float*)Cout)[(size_t)(rr + t) * N + cc] = v;
        else
          ((USH*)Cout)[(size_t)(rr + t) * N + cc] = f2bf(v);
      }
    }
  }
}

// ---------------- V transpose: vT[bh][dh][s] = qkv[b][s][1024 + h*64 + dh] ----------------
__global__ __launch_bounds__(256) void vtrans(const USH* __restrict__ qkv,
                                              USH* __restrict__ vT) {
  __shared__ __align__(16) USH t[64][72];
  const int bh = blockIdx.y, b = bh >> 3, h = bh & 7;
  const int s0 = blockIdx.x * 64;
  const int tid = threadIdx.x;
  const int r = tid >> 4, c4 = (tid & 15) * 4;
#pragma unroll
  for (int i = 0; i < 4; i++) {
    int row = r + i * 16;
    *(ushort4v*)&t[row][c4] =
        *(const ushort4v*)&qkv[(size_t)(b * 4096 + s0 + row) * 1536 + 1024 + h * 64 + c4];
  }
  __syncthreads();
  const int d = tid >> 2, sb = (tid & 3) * 16;
  size_t ob = (size_t)(bh * 64 + d) * 4096 + s0 + sb;
#pragma unroll
  for (int half = 0; half < 2; half++) {
    ushort8v o;
#pragma unroll
    for (int k = 0; k < 8; k++) o[k] = t[sb + half * 8 + k][d];
    *(ushort8v*)&vT[ob + half * 8] = o;
  }
}

// ---------------- Flash attention v6: r2 structure + defer-max gate (only change) ----------------
__global__ __launch_bounds__(256, 3) void attn_fwd(const USH* __restrict__ qkv,
                                                   const USH* __restrict__ vT,
                                                   USH* __restrict__ attno) {
  __shared__ __align__(16) USH Ks[2][64 * 64];   // 16 KB
  __shared__ __align__(16) USH Vs[2][64 * 64];   // 16 KB
  __shared__ __align__(16) USH Ps[4][32 * 64];   // 16 KB (per-wave P)

  // XCD swizzle: all 32 q-blocks of a bh share an XCD (flat%8 constant)
  const int fb = blockIdx.x;
  const int b3 = fb & 7;
  const int rest = fb >> 3;
  const int qb = rest & 31;
  const int bh = b3 + 8 * (rest >> 5);
  const int b = bh >> 3, h = bh & 7;

  const int wid = threadIdx.x >> 6, lane = threadIdx.x & 63;
  const int lmod = lane & 15, ldiv = lane >> 4;
  const int ksw = lmod & 7;
  const int qrow0 = qb * 128 + wid * 32;

  short8 qf00, qf01, qf10, qf11;
  {
    const USH* qp = qkv + (size_t)(b * 4096 + qrow0 + lmod) * 1536 + h * 64 + ldiv * 8;
    qf00 = *(const short8*)qp;
    qf01 = *(const short8*)(qp + 32);
    qp += (size_t)16 * 1536;
    qf10 = *(const short8*)qp;
    qf11 = *(const short8*)(qp + 32);
  }

  short8 ones;
#pragma unroll
  for (int i = 0; i < 8; i++) ones[i] = (short)0x3F80;  // bf16 1.0

  f32x4 acc0[4], acc1[4];
#pragma unroll
  for (int n = 0; n < 4; n++) {
    acc0[n] = (f32x4){0.f, 0.f, 0.f, 0.f};
    acc1[n] = (f32x4){0.f, 0.f, 0.f, 0.f};
  }
  f32x4 l0 = (f32x4){0.f, 0.f, 0.f, 0.f}, l1 = l0;
  f32x4 m0 = (f32x4){-1e30f, -1e30f, -1e30f, -1e30f}, m1 = m0;

  const USH* kbase = qkv + (size_t)b * 4096 * 1536 + 512 + h * 64;
  const USH* vbase = vT + (size_t)bh * 64 * 4096;
  const int srow = lane >> 3;
  const int scol = ((lane & 7) ^ srow) * 8;
  const float K2 = 0.18033688011112042f;  // log2(e)/8

  auto stage = [&](int bu, int k0) {
#pragma unroll
    for (int i = 0; i < 2; ++i) {
      int r0 = wid * 16 + i * 8;
      int r = r0 + srow;
      gload16(kbase + (size_t)(k0 + r) * 1536 + scol, &Ks[bu][r0 * 64]);
      gload16(vbase + (size_t)r * 4096 + k0 + scol, &Vs[bu][r0 * 64]);
    }
  };

  stage(0, 0);

  for (int t = 0; t < 64; ++t) {
    const int cur = t & 1;
    __syncthreads();
    if (t < 63) stage(cur ^ 1, (t + 1) * 64);

    const USH* Kc = &Ks[cur][0];
    const USH* Vc = &Vs[cur][0];
    USH* Pw = &Ps[wid][0];

    // ---- QK^T (r2-verified layout: s[n][j] -> q = ldiv*4+j, k = n*16+lmod) ----
    f32x4 s0[4], s1[4];
#pragma unroll
    for (int n = 0; n < 4; n++) {
      s0[n] = (f32x4){0.f, 0.f, 0.f, 0.f};
      s1[n] = (f32x4){0.f, 0.f, 0.f, 0.f};
    }
#pragma unroll
    for (int n = 0; n < 4; n++) {
      const USH* kr = Kc + (n * 16 + lmod) * 64;
      short8 kf0 = *(const short8*)(kr + ((ldiv ^ ksw) << 3));
      short8 kf1 = *(const short8*)(kr + (((4 + ldiv) ^ ksw) << 3));
      s0[n] = mfma16(qf00, kf0, s0[n]);
      s0[n] = mfma16(qf01, kf1, s0[n]);
      s1[n] = mfma16(qf10, kf0, s1[n]);
      s1[n] = mfma16(qf11, kf1, s1[n]);
    }

    // ---- defer-max gate (T13): skip max-reduce + rescale unless some row's
    // tile max exceeds m+64 (raw units; = 8 post-scale, P <= e^8). Skipped-path
    // math is exact: P, acc, l all use the same (stale) m.
    f32x4 pm0 = vmax4(vmax4(s0[0], s0[1]), vmax4(s0[2], s0[3]));
    f32x4 pm1 = vmax4(vmax4(s1[0], s1[1]), vmax4(s1[2], s1[3]));
    bool ok = true;
#pragma unroll
    for (int j = 0; j < 4; j++)
      ok = ok && (pm0[j] <= m0[j] + 64.f) && (pm1[j] <= m1[j] + 64.f);
    if (!__all(ok)) {
      // r2's max/alpha/rescale path, verbatim (pm = per-lane n-tree max)
      f32x4 al0, al1;
#pragma unroll
      for (int j = 0; j < 4; j++) {
        float v = rowmax16(pm0[j]);
        float mn = fmaxf(m0[j], v);
        al0[j] = exp2f((m0[j] - mn) * K2);
        m0[j] = mn;
      }
#pragma unroll
      for (int j = 0; j < 4; j++) {
        float v = rowmax16(pm1[j]);
        float mn = fmaxf(m1[j], v);
        al1[j] = exp2f((m1[j] - mn) * K2);
        m1[j] = mn;
      }
#pragma unroll
      for (int n = 0; n < 4; n++) {
        acc0[n] *= al0;
        acc1[n] *= al1;
      }
      l0 *= al0;
      l1 *= al1;
    }

    // ---- P = exp2((s-m)*K2) -> swizzled per-wave LDS (r2 verbatim) ----
#pragma unroll
    for (int n = 0; n < 4; n++) {
#pragma unroll
      for (int j = 0; j < 4; j++) {
        int r = ldiv * 4 + j;
        int col = n * 16 + lmod;
        Pw[(r * 64 + col) ^ ((r & 7) << 3)] = f2bf(exp2f((s0[n][j] - m0[j]) * K2));
        Pw[((16 + r) * 64 + col) ^ ((r & 7) << 3)] = f2bf(exp2f((s1[n][j] - m1[j]) * K2));
      }
    }

    // ---- PV (+ row-sum via ones-MFMA) (r2 verbatim) ----
#pragma unroll
    for (int kc = 0; kc < 2; kc++) {
      const int off = kc * 32 + ldiv * 8;
      short8 pf0 = *(const short8*)&Pw[(lmod * 64 + off) ^ (ksw << 3)];
      short8 pf1 = *(const short8*)&Pw[((16 + lmod) * 64 + off) ^ (ksw << 3)];
      l0 = mfma16(pf0, ones, l0);
      l1 = mfma16(pf1, ones, l1);
#pragma unroll
      for (int n = 0; n < 4; n++) {
        const USH* vr = Vc + (n * 16 + lmod) * 64;
        short8 vf = *(const short8*)(vr + (((kc * 4 + ldiv) ^ ksw) << 3));
        acc0[n] = mfma16(pf0, vf, acc0[n]);
        acc1[n] = mfma16(pf1, vf, acc1[n]);
      }
    }
  }

  // ---- epilogue ----
  float iv0[4], iv1[4];
#pragma unroll
  for (int j = 0; j < 4; j++) {
    iv0[j] = 1.0f / l0[j];
    iv1[j] = 1.0f / l1[j];
  }
  USH* ob = attno + (size_t)(b * 4096 + qrow0) * 512 + h * 64;
#pragma unroll
  for (int n = 0; n < 4; n++) {
#pragma unroll
    for (int j = 0; j < 4; j++) {
      ob[(size_t)(ldiv * 4 + j) * 512 + n * 16 + lmod] = f2bf(acc0[n][j] * iv0[j]);
      ob[(size_t)(16 + ldiv * 4 + j) * 512 + n * 16 + lmod] = f2bf(acc1[n][j] * iv1[j]);
    }
  }
}

// ---------------- launch ----------------
extern "C" void kernel_launch(void* const* d_in, const int* in_sizes, int n_in,
                              void* d_out, int out_size, void* d_ws, size_t ws_size,
                              hipStream_t stream) {
  const float* x = (const float*)d_in[0];      // (4,4096,512)
  const float* w_in = (const float*)d_in[1];   // (1536,512)
  const float* b_in = (const float*)d_in[2];   // (1536)
  const float* w_out = (const float*)d_in[3];  // (512,512)
  const float* b_out = (const float*)d_in[4];  // (512)
  float* out = (float*)d_out;                  // (4,4096,512) fp32

  char* ws = (char*)d_ws;
  USH* xb = (USH*)(ws);                        // 16 MB  (reused as attno later)
  USH* winb = (USH*)(ws + 16777216);           // 1.5 MB
  USH* woutb = (USH*)(ws + 18350080);          // 0.5 MB
  USH* qkv = (USH*)(ws + 18874368);            // 48 MB
  USH* vT = (USH*)(ws + 69206016);             // 16 MB
  USH* attno = xb;                             // alias: xb dead after gemm1

  cvt_bf16<<<8192, 256, 0, stream>>>(x, xb, 2097152);
  cvt_bf16<<<768, 256, 0, stream>>>(w_in, winb, 196608);
  cvt_bf16<<<256, 256, 0, stream>>>(w_out, woutb, 65536);

  gemm_bt<false><<<dim3(128, 12), 256, 0, stream>>>(xb, winb, b_in, qkv, 16384, 1536, 512);
  vtrans<<<dim3(64, 32), 256, 0, stream>>>(qkv, vT);
  attn_fwd<<<1024, 256, 0, stream>>>(qkv, vT, attno);
  gemm_bt<true><<<dim3(128, 4), 256, 0, stream>>>(attno, woutb, b_out, out, 16384, 512, 512);
}